// Round 5
// baseline (605.702 us; speedup 1.0000x reference)
//
#include <hip/hip_runtime.h>
#include <math.h>

// ws layout (float offsets)
#define SB_OFF   0          // packed strips [2][8][32][1024] = 524288 floats
#define E_OFF    524288     // e    [128][2048]      = 262144 floats
#define YP_OFF   786432     // ypart[8][64][128][16] = 1048576 floats
#define FLAG_OFF 1835008    // flags[256][16] uint (64B-padded per block)
// strip record layout (1024 floats/tile): HT=0 HB=128 VL=256 VR=512 CTL=768 CTR=784 CBL=800 CBR=816

__device__ __forceinline__ float fast_tanh(float x) {
  x = fminf(fmaxf(x, -15.f), 15.f);
  float ex = __expf(2.f * x);
  return __fdividef(ex - 1.f, ex + 1.f);
}

// Cross-XCD coherent data path: relaxed AGENT-scope atomics are serviced at the
// coherent point (L2-bypass) — no buffer_wbl2 / buffer_inv needed.
__device__ __forceinline__ float2 aload_f2(const float* p) {
  unsigned long long v = __hip_atomic_load((const unsigned long long*)p,
                                           __ATOMIC_RELAXED, __HIP_MEMORY_SCOPE_AGENT);
  float2 r;
  r.x = __uint_as_float((unsigned)v);
  r.y = __uint_as_float((unsigned)(v >> 32));
  return r;
}
__device__ __forceinline__ void astore_f2(float* p, float a, float b) {
  unsigned long long v =
      ((unsigned long long)__float_as_uint(b) << 32) | (unsigned long long)__float_as_uint(a);
  __hip_atomic_store((unsigned long long*)p, v, __ATOMIC_RELAXED, __HIP_MEMORY_SCOPE_AGENT);
}

// ---------------- K0: zero flags, compute embed e = (X@W^T)*mask_coarse
__global__ __launch_bounds__(256) void prep_kernel(
    const float* __restrict__ X, const float* __restrict__ W_embed,
    const float* __restrict__ mask_coarse, float* __restrict__ ws)
{
  const int tid = threadIdx.x, bid = blockIdx.x;  // grid = 128
  float* eb = ws + E_OFF;
  unsigned* flags = (unsigned*)(ws + FLAG_OFF);
  if (bid < 16) flags[bid * 256 + tid] = 0;   // 256 blocks x 16 uints

  // embed: block handles 16 output rows (o), thread: one o x 8 t's
  const int o  = bid * 16 + (tid & 15);
  const int t0 = (tid >> 4) * 8;
  const float4* Wf4 = (const float4*)W_embed + (size_t)o * 128;
  const float4* Xf4 = (const float4*)X;
  float acc[8];
#pragma unroll
  for (int i = 0; i < 8; ++i) acc[i] = 0.f;
  for (int k4 = 0; k4 < 128; ++k4) {
    float4 wv = Wf4[k4];
#pragma unroll
    for (int tt = 0; tt < 8; ++tt) {
      float4 xv = Xf4[(size_t)(t0 + tt) * 128 + k4];
      acc[tt] = fmaf(wv.x, xv.x, fmaf(wv.y, xv.y, fmaf(wv.z, xv.z, fmaf(wv.w, xv.w, acc[tt]))));
    }
  }
  float mc = mask_coarse[o & 255];
#pragma unroll
  for (int tt = 0; tt < 8; ++tt)
    eb[(size_t)(t0 + tt) * 2048 + o] = acc[tt] * mc;
}

// ---------------- K1: persistent scan. 256 blocks = 8 ch x (4x8 tiles of 64x32)
// State persistent in LDS; 4-wide boundary ring exchanged via PACKED coherent strips.
__global__ __launch_bounds__(256, 1) void scan_kernel(
    const float* __restrict__ mask_fine, const float* __restrict__ W_deconv,
    const float* __restrict__ w1, const float* __restrict__ w2,
    const float* __restrict__ w_out, float* __restrict__ ws)
{
  __shared__ float zin[72 * 44];      // persistent state tile + halo (stride 44)
  __shared__ float redbuf[256 * 33];  // readout reduction
  __shared__ float pb[8 * 33];

  const int tid  = threadIdx.x;
  const int bid  = blockIdx.x;
  const int ch   = bid >> 5;
  const int tile = bid & 31;
  const int tI = tile >> 3, tJ = tile & 7;   // 4 x 8 tile grid
  const int r0 = tI << 6, c0 = tJ << 5;
  const int lr = tid >> 3;          // 0..31
  const int lc = (tid & 7) << 2;    // 0,4..28

  float* Zb = ws + SB_OFF;
  const float* eb = ws + E_OFF;
  float* yp = ws + YP_OFF;
  unsigned* flags_all = (unsigned*)(ws + FLAG_OFF);
  unsigned* myf = flags_all + bid * 16;

  // toroidal 8-neighborhood flag pointers (circular conv wrap)
  unsigned* nfp = nullptr;
  if (tid < 8) {
    const int dI[8] = {-1, -1, -1, 0, 0, 1, 1, 1};
    const int dJ[8] = {-1, 0, 1, -1, 1, -1, 0, 1};
    int nI = (tI + dI[tid]) & 3;
    int nJ = (tJ + dJ[tid]) & 7;
    nfp = flags_all + (ch * 32 + nI * 8 + nJ) * 16;
  }
  // neighbor strip-record offsets (buffer term added per step)
  auto recoff = [&](int di, int dj) {
    int nI2 = (tI + di) & 3, nJ2 = (tJ + dj) & 7;
    return (ch * 32 + nI2 * 8 + nJ2) << 10;
  };
  const int offU  = recoff(-1, 0), offD  = recoff(1, 0);
  const int offL  = recoff(0, -1), offR  = recoff(0, 1);
  const int offUL = recoff(-1, -1), offUR = recoff(-1, 1);
  const int offDL = recoff(1, -1),  offDR = recoff(1, 1);
  const int myoff = (ch * 32 + tile) << 10;

  // per-thread fixed constants (same (a,b) position every step)
  const int a16 = lr & 15;
  const int b16 = lc & 15;
  const int i0  = (r0 + lr) >> 4;
  const int jj  = (c0 + lc) >> 4;
  float4 wd[8];
#pragma unroll
  for (int c = 0; c < 8; ++c)
    wd[c] = *(const float4*)&W_deconv[(((c * 8 + ch) * 16) + a16) * 16 + b16];
  float4 mf0 = *(const float4*)&mask_fine[(size_t)(r0 + lr) * 256 + c0 + lc];
  float4 mf1 = *(const float4*)&mask_fine[(size_t)(r0 + lr + 32) * 256 + c0 + lc];
  float4 wo[16];
#pragma unroll
  for (int oc = 0; oc < 16; ++oc)
    wo[oc] = *(const float4*)&w_out[(((oc * 8 + ch) * 32) + lr) * 32 + lc];
  float w1s[9], w2s[25];
#pragma unroll
  for (int k = 0; k < 9; ++k)
    w1s[k] = __uint_as_float(__builtin_amdgcn_readfirstlane(__float_as_uint(w1[ch * 9 + k])));
#pragma unroll
  for (int k = 0; k < 25; ++k)
    w2s[k] = __uint_as_float(__builtin_amdgcn_readfirstlane(__float_as_uint(w2[ch * 25 + k])));

  // init persistent state (Z0 = 0, incl. halo)
  for (int k = tid; k < 72 * 44; k += 256) zin[k] = 0.f;
  __syncthreads();

  auto load_row = [&](int zr, float* w) {
    float4 A  = *(const float4*)&zin[zr * 44 + lc];
    float4 B  = *(const float4*)&zin[zr * 44 + lc + 4];
    float4 Cq = *(const float4*)&zin[zr * 44 + lc + 8];
    w[0]=A.x; w[1]=A.y; w[2]=A.z; w[3]=A.w;
    w[4]=B.x; w[5]=B.y; w[6]=B.z; w[7]=B.w;
    w[8]=Cq.x; w[9]=Cq.y; w[10]=Cq.z; w[11]=Cq.w;
  };
  auto k2row = [&](const float* w, int a, float* c2a) {
#pragma unroll
    for (int j = 0; j < 4; ++j)
#pragma unroll
      for (int b = 0; b < 5; ++b)
        c2a[j] = fmaf(w[j + 2 * b], w2s[a * 5 + b], c2a[j]);
  };
  auto k1row = [&](const float* w, int a, float* c1a) {
#pragma unroll
    for (int j = 0; j < 4; ++j)
#pragma unroll
      for (int b = 0; b < 3; ++b)
        c1a[j] = fmaf(w[j + 3 + b], w1s[a * 3 + b], c1a[j]);
  };

  for (int t = 0; t < 128; ++t) {
    float* sb = Zb + (size_t)((t + 1) & 1) * 262144;   // strip buffer for Z_{t+1}
    float* myrec = sb + myoff;

    // input-path e values for this step (plain cached loads; eb is read-only)
    float ev[2][8];
#pragma unroll
    for (int h = 0; h < 2; ++h) {
      int ih = i0 + 2 * h;
#pragma unroll
      for (int c = 0; c < 8; ++c)
        ev[h][c] = eb[(size_t)t * 2048 + c * 256 + ih * 16 + jj];
    }

    // ---- compute Z_{t+1} into registers (reads zin = Z_t incl halo)
    float zvv[2][4];
    float racc[32];
#pragma unroll
    for (int h = 0; h < 2; ++h) {
      const int lrh = lr + 32 * h;
      float c1a[4] = {0,0,0,0}, c2a[4] = {0,0,0,0};
      float wrow[12];
      load_row(lrh + 0, wrow); k2row(wrow, 0, c2a);
      load_row(lrh + 2, wrow); k2row(wrow, 1, c2a);
      load_row(lrh + 3, wrow); k1row(wrow, 0, c1a);
      load_row(lrh + 4, wrow); k1row(wrow, 1, c1a); k2row(wrow, 2, c2a);
      load_row(lrh + 5, wrow); k1row(wrow, 2, c1a);
      load_row(lrh + 6, wrow); k2row(wrow, 3, c2a);
      load_row(lrh + 8, wrow); k2row(wrow, 4, c2a);

      const float* mfp = (h == 0) ? (const float*)&mf0 : (const float*)&mf1;
#pragma unroll
      for (int j = 0; j < 4; ++j) {
        float u = 0.f;
#pragma unroll
        for (int c = 0; c < 8; ++c)
          u = fmaf(ev[h][c], ((const float*)&wd[c])[j], u);
        float val = fmaf(0.9f, c1a[j], fmaf(0.1f, c2a[j], mfp[j] * u));
        zvv[h][j] = fast_tanh(val);
      }
#pragma unroll
      for (int oc = 0; oc < 16; ++oc) {
        const float* wop = (const float*)&wo[oc];
        racc[h * 16 + oc] =
            fmaf(zvv[h][0], wop[0],
                 fmaf(zvv[h][1], wop[1], fmaf(zvv[h][2], wop[2], zvv[h][3] * wop[3])));
      }
    }

    __syncthreads();  // all reads of Z_t from zin complete

    // ---- commit: full tile -> LDS; boundary -> PACKED coherent strip record
#pragma unroll
    for (int h = 0; h < 2; ++h) {
      const int lrh = lr + 32 * h;
      *(float4*)&zin[(4 + lrh) * 44 + 4 + lc] =
          make_float4(zvv[h][0], zvv[h][1], zvv[h][2], zvv[h][3]);
      float a0 = zvv[h][0], a1 = zvv[h][1], a2 = zvv[h][2], a3 = zvv[h][3];
      if (h == 0 && lr < 4) {              // Htop [4][32]
        float* p = myrec + 0 + lr * 32 + lc;
        astore_f2(p, a0, a1); astore_f2(p + 2, a2, a3);
      }
      if (h == 1 && lr >= 28) {            // Hbot [4][32]
        float* p = myrec + 128 + (lr - 28) * 32 + lc;
        astore_f2(p, a0, a1); astore_f2(p + 2, a2, a3);
      }
      if (lc == 0) {                       // Vleft [64][4]
        float* p = myrec + 256 + lrh * 4;
        astore_f2(p, a0, a1); astore_f2(p + 2, a2, a3);
      }
      if (lc == 28) {                      // Vright [64][4]
        float* p = myrec + 512 + lrh * 4;
        astore_f2(p, a0, a1); astore_f2(p + 2, a2, a3);
      }
      if (h == 0 && lr < 4 && lc == 0)  {  // CTL [4][4]
        float* p = myrec + 768 + lr * 4;
        astore_f2(p, a0, a1); astore_f2(p + 2, a2, a3);
      }
      if (h == 0 && lr < 4 && lc == 28) {  // CTR
        float* p = myrec + 784 + lr * 4;
        astore_f2(p, a0, a1); astore_f2(p + 2, a2, a3);
      }
      if (h == 1 && lr >= 28 && lc == 0) { // CBL
        float* p = myrec + 800 + (lr - 28) * 4;
        astore_f2(p, a0, a1); astore_f2(p + 2, a2, a3);
      }
      if (h == 1 && lr >= 28 && lc == 28) {// CBR
        float* p = myrec + 816 + (lr - 28) * 4;
        astore_f2(p, a0, a1); astore_f2(p + 2, a2, a3);
      }
    }

    __syncthreads();  // per-wave vmcnt(0) before barrier: strip stores drained

    // arrive early — neighbors can proceed while we do the readout reduction
    if (t < 127 && tid == 0)
      __hip_atomic_store(myf, (unsigned)(t + 1), __ATOMIC_RELAXED, __HIP_MEMORY_SCOPE_AGENT);

    // ---- per-step readout reduction: 256 threads x 32 (patch,oc) -> 32 values
#pragma unroll
    for (int k = 0; k < 32; ++k) redbuf[tid * 33 + k] = racc[k];
    __syncthreads();
    {
      int col = tid & 31, chunk = tid >> 5;
      float s = 0.f;
#pragma unroll
      for (int r = 0; r < 32; ++r) s += redbuf[(chunk * 32 + r) * 33 + col];
      pb[chunk * 33 + col] = s;
    }
    __syncthreads();
    if (tid < 32) {
      float s = 0.f;
#pragma unroll
      for (int k = 0; k < 8; ++k) s += pb[k * 33 + tid];
      int p = tid >> 4, oc = tid & 15;
      yp[(((size_t)ch * 64 + (2 * tI + p) * 8 + tJ) * 128 + t) * 16 + oc] = s;
    }

    if (t < 127) {
      // wait for the 8 toroidal neighbors to publish step t+1 strips
      if (tid < 8) {
        int spins = 0;
        while (__hip_atomic_load(nfp, __ATOMIC_RELAXED, __HIP_MEMORY_SCOPE_AGENT) <
               (unsigned)(t + 1)) {
          __builtin_amdgcn_s_sleep(1);
          if (++spins > (1 << 20)) break;  // fail loud rather than hang
        }
      }
      __syncthreads();

      // ---- load halo ring (416 f2) from neighbors' PACKED strips
      // zin columns: 0..3 left halo | 4..35 tile | 36..39 right halo
#pragma unroll
      for (int pass = 0; pass < 2; ++pass) {
        int u = tid + (pass << 8);
        if (u < 416) {
          const float* src;
          int dst;
          if (u < 64) {            // top rows 0..3 cols 4..35  <- U.Hbot
            int row = u >> 4, cp = (u & 15) << 1;
            src = sb + offU + 128 + row * 32 + cp;
            dst = row * 44 + 4 + cp;
          } else if (u < 128) {    // bottom rows 68..71        <- D.Htop
            int v = u - 64; int row = v >> 4, cp = (v & 15) << 1;
            src = sb + offD + 0 + row * 32 + cp;
            dst = (68 + row) * 44 + 4 + cp;
          } else if (u < 256) {    // left rows 4..67 cols 0..3 <- L.Vright
            int v = u - 128; int r = v >> 1, c = (v & 1) << 1;
            src = sb + offL + 512 + r * 4 + c;
            dst = (4 + r) * 44 + c;
          } else if (u < 384) {    // right rows 4..67 cols 36..39 <- R.Vleft
            int v = u - 256; int r = v >> 1, c = (v & 1) << 1;
            src = sb + offR + 256 + r * 4 + c;
            dst = (4 + r) * 44 + 36 + c;
          } else {                 // 4 corners, 8 f2 each
            int v = u - 384; int corner = v >> 3; int k = v & 7;
            int row = k >> 1, c = (k & 1) << 1;
            if (corner == 0)      { src = sb + offUL + 816 + row * 4 + c; dst = row * 44 + c; }
            else if (corner == 1) { src = sb + offUR + 800 + row * 4 + c; dst = row * 44 + 36 + c; }
            else if (corner == 2) { src = sb + offDL + 784 + row * 4 + c; dst = (68 + row) * 44 + c; }
            else                  { src = sb + offDR + 768 + row * 4 + c; dst = (68 + row) * 44 + 36 + c; }
          }
          float2 v2 = aload_f2(src);
          *(float2*)&zin[dst] = v2;
        }
      }
      __syncthreads();
    }
  }
}

// ---------------- K2: sum channel partials + bias -> out [128,16,8,8] flat
__global__ __launch_bounds__(256) void final_kernel(
    const float* __restrict__ b_out, const float* __restrict__ ws, float* __restrict__ out)
{
  int idx = blockIdx.x * 256 + threadIdx.x;  // 131072
  int t = idx >> 10;
  int rem = idx & 1023;
  int oc = rem >> 6;
  int IJ = rem & 63;
  const float* yp = ws + YP_OFF;
  float s = b_out[oc];
#pragma unroll
  for (int c = 0; c < 8; ++c)
    s += yp[(((size_t)c * 64 + IJ) * 128 + t) * 16 + oc];
  out[idx] = s;
}

extern "C" void kernel_launch(void* const* d_in, const int* in_sizes, int n_in,
                              void* d_out, int out_size, void* d_ws, size_t ws_size,
                              hipStream_t stream) {
  const float* X           = (const float*)d_in[0];
  const float* W_embed     = (const float*)d_in[1];
  const float* mask_coarse = (const float*)d_in[2];
  const float* mask_fine   = (const float*)d_in[3];
  const float* W_deconv    = (const float*)d_in[4];
  const float* w1          = (const float*)d_in[5];
  const float* w2          = (const float*)d_in[6];
  const float* w_out       = (const float*)d_in[7];
  const float* b_out       = (const float*)d_in[8];
  float* ws  = (float*)d_ws;
  float* out = (float*)d_out;

  prep_kernel<<<dim3(128), dim3(256), 0, stream>>>(X, W_embed, mask_coarse, ws);
  scan_kernel<<<dim3(256), dim3(256), 0, stream>>>(mask_fine, W_deconv, w1, w2, w_out, ws);
  final_kernel<<<dim3(512), dim3(256), 0, stream>>>(b_out, ws, out);
}

// Round 6
// 589.685 us; speedup vs baseline: 1.0272x; 1.0272x over previous
//
#include <hip/hip_runtime.h>
#include <math.h>

// ws layout (float offsets)
#define SB_OFF   0          // packed strips [2][8][32][1024] = 524288 floats
#define E_OFF    524288     // e    [128][2048]      = 262144 floats
#define YP_OFF   786432     // ypart[8][64][128][16] = 1048576 floats
#define FLAG_OFF 1835008    // flags[256][16] uint (64B-padded per block)
// strip record layout (1024 floats/tile): HT=0 HB=128 VL=256 VR=512 CTL=768 CTR=784 CBL=800 CBR=816

__device__ __forceinline__ float fast_tanh(float x) {
  x = fminf(fmaxf(x, -15.f), 15.f);
  float ex = __expf(2.f * x);
  return __fdividef(ex - 1.f, ex + 1.f);
}

// Cross-XCD coherent data path: relaxed AGENT-scope atomics serviced at the
// coherent point (L2-bypass) — no buffer_wbl2 / buffer_inv needed.
__device__ __forceinline__ float2 aload_f2(const float* p) {
  unsigned long long v = __hip_atomic_load((const unsigned long long*)p,
                                           __ATOMIC_RELAXED, __HIP_MEMORY_SCOPE_AGENT);
  float2 r;
  r.x = __uint_as_float((unsigned)v);
  r.y = __uint_as_float((unsigned)(v >> 32));
  return r;
}
__device__ __forceinline__ void astore_f2(float* p, float a, float b) {
  unsigned long long v =
      ((unsigned long long)__float_as_uint(b) << 32) | (unsigned long long)__float_as_uint(a);
  __hip_atomic_store((unsigned long long*)p, v, __ATOMIC_RELAXED, __HIP_MEMORY_SCOPE_AGENT);
}

// ---------------- K0: zero flags, compute embed e = (X@W^T)*mask_coarse
__global__ __launch_bounds__(256) void prep_kernel(
    const float* __restrict__ X, const float* __restrict__ W_embed,
    const float* __restrict__ mask_coarse, float* __restrict__ ws)
{
  const int tid = threadIdx.x, bid = blockIdx.x;  // grid = 128
  float* eb = ws + E_OFF;
  unsigned* flags = (unsigned*)(ws + FLAG_OFF);
  if (bid < 16) flags[bid * 256 + tid] = 0;   // 256 blocks x 16 uints

  const int o  = bid * 16 + (tid & 15);
  const int t0 = (tid >> 4) * 8;
  const float4* Wf4 = (const float4*)W_embed + (size_t)o * 128;
  const float4* Xf4 = (const float4*)X;
  float acc[8];
#pragma unroll
  for (int i = 0; i < 8; ++i) acc[i] = 0.f;
  for (int k4 = 0; k4 < 128; ++k4) {
    float4 wv = Wf4[k4];
#pragma unroll
    for (int tt = 0; tt < 8; ++tt) {
      float4 xv = Xf4[(size_t)(t0 + tt) * 128 + k4];
      acc[tt] = fmaf(wv.x, xv.x, fmaf(wv.y, xv.y, fmaf(wv.z, xv.z, fmaf(wv.w, xv.w, acc[tt]))));
    }
  }
  float mc = mask_coarse[o & 255];
#pragma unroll
  for (int tt = 0; tt < 8; ++tt)
    eb[(size_t)(t0 + tt) * 2048 + o] = acc[tt] * mc;
}

// ---------------- K1: persistent scan. 256 blocks x 512 threads.
// 8 ch x (4x8 tiles of 64x32); 1 float4-group (4 px) per thread.
__global__ __launch_bounds__(512, 2) void scan_kernel(
    const float* __restrict__ mask_fine, const float* __restrict__ W_deconv,
    const float* __restrict__ w1, const float* __restrict__ w2,
    const float* __restrict__ w_out, float* __restrict__ ws)
{
  __shared__ float zin[72 * 44];      // persistent state tile + halo (stride 44)
  __shared__ float rowbuf[64 * 19];   // per-row readout partials (16 oc, stride 19)

  const int tid  = threadIdx.x;       // 0..511
  const int bid  = blockIdx.x;
  const int ch   = bid >> 5;
  const int tile = bid & 31;
  const int tI = tile >> 3, tJ = tile & 7;   // 4 x 8 tile grid
  const int r0 = tI << 6, c0 = tJ << 5;
  const int row = tid >> 3;           // 0..63
  const int cg  = tid & 7;
  const int lc  = cg << 2;            // 0,4..28

  float* Zb = ws + SB_OFF;
  const float* eb = ws + E_OFF;
  float* yp = ws + YP_OFF;
  unsigned* flags_all = (unsigned*)(ws + FLAG_OFF);
  unsigned* myf = flags_all + bid * 16;
  const int myoff = (ch * 32 + tile) << 10;

  // ---- per-thread fixed constants
  const int a16 = row & 15;
  const int b16 = lc & 15;
  const int i0  = (r0 + row) >> 4;
  const int jj  = (c0 + lc) >> 4;
  float4 wd[8];
#pragma unroll
  for (int c = 0; c < 8; ++c)
    wd[c] = *(const float4*)&W_deconv[(((c * 8 + ch) * 16) + a16) * 16 + b16];
  float4 mf = *(const float4*)&mask_fine[(size_t)(r0 + row) * 256 + c0 + lc];
  float4 wo[16];
#pragma unroll
  for (int oc = 0; oc < 16; ++oc)
    wo[oc] = *(const float4*)&w_out[(((oc * 8 + ch) * 32) + (row & 31)) * 32 + lc];
  float w1s[9], w2s[25];
#pragma unroll
  for (int k = 0; k < 9; ++k)
    w1s[k] = __uint_as_float(__builtin_amdgcn_readfirstlane(__float_as_uint(w1[ch * 9 + k])));
#pragma unroll
  for (int k = 0; k < 25; ++k)
    w2s[k] = __uint_as_float(__builtin_amdgcn_readfirstlane(__float_as_uint(w2[ch * 25 + k])));

  // ---- per-thread fixed halo-exchange assignment (u = tid, 416 f2 transfers)
  int h_soff = 0, h_dst = 0, h_nrec = 0;
  const unsigned* h_flag = nullptr;
  const bool has_halo = (tid < 416);
  {
    int u = tid, di = 0, dj = 0;
    if (u < 64) {            // top rows 0..3 cols 4..35  <- U.Hbot
      int r = u >> 4, cp = (u & 15) << 1;
      di = -1; dj = 0; h_soff = 128 + r * 32 + cp; h_dst = r * 44 + 4 + cp;
    } else if (u < 128) {    // bottom rows 68..71        <- D.Htop
      int v = u - 64; int r = v >> 4, cp = (v & 15) << 1;
      di = 1; dj = 0; h_soff = 0 + r * 32 + cp; h_dst = (68 + r) * 44 + 4 + cp;
    } else if (u < 256) {    // left rows 4..67 cols 0..3 <- L.Vright
      int v = u - 128; int r = v >> 1, c = (v & 1) << 1;
      di = 0; dj = -1; h_soff = 512 + r * 4 + c; h_dst = (4 + r) * 44 + c;
    } else if (u < 384) {    // right rows 4..67 cols 36..39 <- R.Vleft
      int v = u - 256; int r = v >> 1, c = (v & 1) << 1;
      di = 0; dj = 1; h_soff = 256 + r * 4 + c; h_dst = (4 + r) * 44 + 36 + c;
    } else if (u < 416) {    // 4 corners, 8 f2 each
      int v = u - 384; int corner = v >> 3; int k = v & 7;
      int r = k >> 1, c = (k & 1) << 1;
      if (corner == 0)      { di = -1; dj = -1; h_soff = 816 + r * 4 + c; h_dst = r * 44 + c; }
      else if (corner == 1) { di = -1; dj = 1;  h_soff = 800 + r * 4 + c; h_dst = r * 44 + 36 + c; }
      else if (corner == 2) { di = 1;  dj = -1; h_soff = 784 + r * 4 + c; h_dst = (68 + r) * 44 + c; }
      else                  { di = 1;  dj = 1;  h_soff = 768 + r * 4 + c; h_dst = (68 + r) * 44 + 36 + c; }
    }
    int nI = (tI + di) & 3, nJ = (tJ + dj) & 7;
    h_nrec = (ch * 32 + nI * 8 + nJ) << 10;
    h_flag = flags_all + (ch * 32 + nI * 8 + nJ) * 16;
  }

  // init persistent state (Z0 = 0, incl. halo)
  for (int k = tid; k < 72 * 44; k += 512) zin[k] = 0.f;
  __syncthreads();

  for (int t = 0; t < 128; ++t) {
    float* sb = Zb + (size_t)((t + 1) & 1) * 262144;   // strip buffer for Z_{t+1}
    float* myrec = sb + myoff;

    // input-path e values (read-only, L2-resident)
    float ev[8];
#pragma unroll
    for (int c = 0; c < 8; ++c)
      ev[c] = eb[(size_t)t * 2048 + c * 256 + i0 * 16 + jj];

    // ---- compute Z_{t+1} for this thread's 4 px (reads zin = Z_t incl halo)
    float c1a[4] = {0, 0, 0, 0}, c2a[4] = {0, 0, 0, 0};
    {
      float w[12];
      auto load_row = [&](int zr) {
        float4 A  = *(const float4*)&zin[zr * 44 + lc];
        float4 B  = *(const float4*)&zin[zr * 44 + lc + 4];
        float4 Cq = *(const float4*)&zin[zr * 44 + lc + 8];
        w[0]=A.x; w[1]=A.y; w[2]=A.z; w[3]=A.w;
        w[4]=B.x; w[5]=B.y; w[6]=B.z; w[7]=B.w;
        w[8]=Cq.x; w[9]=Cq.y; w[10]=Cq.z; w[11]=Cq.w;
      };
      auto k2row = [&](int a) {
#pragma unroll
        for (int j = 0; j < 4; ++j)
#pragma unroll
          for (int b = 0; b < 5; ++b)
            c2a[j] = fmaf(w[j + 2 * b], w2s[a * 5 + b], c2a[j]);
      };
      auto k1row = [&](int a) {
#pragma unroll
        for (int j = 0; j < 4; ++j)
#pragma unroll
          for (int b = 0; b < 3; ++b)
            c1a[j] = fmaf(w[j + 3 + b], w1s[a * 3 + b], c1a[j]);
      };
      load_row(row + 0); k2row(0);
      load_row(row + 2); k2row(1);
      load_row(row + 3); k1row(0);
      load_row(row + 4); k1row(1); k2row(2);
      load_row(row + 5); k1row(2);
      load_row(row + 6); k2row(3);
      load_row(row + 8); k2row(4);
    }
    float zv[4];
    {
      const float* mfp = (const float*)&mf;
#pragma unroll
      for (int j = 0; j < 4; ++j) {
        float u = 0.f;
#pragma unroll
        for (int c = 0; c < 8; ++c)
          u = fmaf(ev[c], ((const float*)&wd[c])[j], u);
        float val = fmaf(0.9f, c1a[j], fmaf(0.1f, c2a[j], mfp[j] * u));
        zv[j] = fast_tanh(val);
      }
    }
    float racc[16];
#pragma unroll
    for (int oc = 0; oc < 16; ++oc) {
      const float* wop = (const float*)&wo[oc];
      racc[oc] = fmaf(zv[0], wop[0], fmaf(zv[1], wop[1], fmaf(zv[2], wop[2], zv[3] * wop[3])));
    }

    __syncthreads();  // A: all reads of Z_t from zin complete

    // ---- commit: tile -> LDS; boundary -> PACKED coherent strip record
    *(float4*)&zin[(4 + row) * 44 + 4 + lc] = make_float4(zv[0], zv[1], zv[2], zv[3]);
    if (row < 4) {                       // Htop [4][32]
      float* p = myrec + 0 + row * 32 + lc;
      astore_f2(p, zv[0], zv[1]); astore_f2(p + 2, zv[2], zv[3]);
    }
    if (row >= 60) {                     // Hbot [4][32]
      float* p = myrec + 128 + (row - 60) * 32 + lc;
      astore_f2(p, zv[0], zv[1]); astore_f2(p + 2, zv[2], zv[3]);
    }
    if (lc == 0) {                       // Vleft [64][4]
      float* p = myrec + 256 + row * 4;
      astore_f2(p, zv[0], zv[1]); astore_f2(p + 2, zv[2], zv[3]);
    }
    if (lc == 28) {                      // Vright [64][4]
      float* p = myrec + 512 + row * 4;
      astore_f2(p, zv[0], zv[1]); astore_f2(p + 2, zv[2], zv[3]);
    }
    if (row < 4 && lc == 0) {            // CTL [4][4]
      float* p = myrec + 768 + row * 4;
      astore_f2(p, zv[0], zv[1]); astore_f2(p + 2, zv[2], zv[3]);
    }
    if (row < 4 && lc == 28) {           // CTR
      float* p = myrec + 784 + row * 4;
      astore_f2(p, zv[0], zv[1]); astore_f2(p + 2, zv[2], zv[3]);
    }
    if (row >= 60 && lc == 0) {          // CBL
      float* p = myrec + 800 + (row - 60) * 4;
      astore_f2(p, zv[0], zv[1]); astore_f2(p + 2, zv[2], zv[3]);
    }
    if (row >= 60 && lc == 28) {         // CBR
      float* p = myrec + 816 + (row - 60) * 4;
      astore_f2(p, zv[0], zv[1]); astore_f2(p + 2, zv[2], zv[3]);
    }

    __syncthreads();  // B: per-wave vmcnt(0) -> all strip stores drained

    // arrive immediately — neighbors can proceed while we reduce + load halo
    if (t < 127 && tid == 0)
      __hip_atomic_store(myf, (unsigned)(t + 1), __ATOMIC_RELAXED, __HIP_MEMORY_SCOPE_AGENT);

    // ---- readout reduction, stage 1: octet butterfly (8 lanes share a row)
#pragma unroll
    for (int m = 1; m <= 4; m <<= 1)
#pragma unroll
      for (int k = 0; k < 16; ++k)
        racc[k] += __shfl_xor(racc[k], m, 64);
    rowbuf[row * 19 + (cg << 1)]     = racc[cg << 1];
    rowbuf[row * 19 + (cg << 1) + 1] = racc[(cg << 1) + 1];

    // ---- fused per-thread poll + halo load (overlaps flag propagation)
    if (t < 127 && has_halo) {
      int spins = 0;
      while (__hip_atomic_load(h_flag, __ATOMIC_RELAXED, __HIP_MEMORY_SCOPE_AGENT) <
             (unsigned)(t + 1)) {
        __builtin_amdgcn_s_sleep(1);
        if (++spins > (1 << 20)) break;  // fail loud rather than hang
      }
      float2 v2 = aload_f2(sb + h_nrec + h_soff);
      *(float2*)&zin[h_dst] = v2;
    }

    __syncthreads();  // E: halo in zin + rowbuf visible

    // ---- stage 2: 32 threads fold 32 rows -> yp (safe: next write is after B)
    if (tid < 32) {
      int p = tid >> 4, oc = tid & 15;
      float s = 0.f;
#pragma unroll
      for (int r = 0; r < 32; ++r) s += rowbuf[(p * 32 + r) * 19 + oc];
      yp[(((size_t)ch * 64 + (2 * tI + p) * 8 + tJ) * 128 + t) * 16 + oc] = s;
    }
  }
}

// ---------------- K2: sum channel partials + bias -> out [128,16,8,8] flat
__global__ __launch_bounds__(256) void final_kernel(
    const float* __restrict__ b_out, const float* __restrict__ ws, float* __restrict__ out)
{
  int idx = blockIdx.x * 256 + threadIdx.x;  // 131072
  int t = idx >> 10;
  int rem = idx & 1023;
  int oc = rem >> 6;
  int IJ = rem & 63;
  const float* yp = ws + YP_OFF;
  float s = b_out[oc];
#pragma unroll
  for (int c = 0; c < 8; ++c)
    s += yp[(((size_t)c * 64 + IJ) * 128 + t) * 16 + oc];
  out[idx] = s;
}

extern "C" void kernel_launch(void* const* d_in, const int* in_sizes, int n_in,
                              void* d_out, int out_size, void* d_ws, size_t ws_size,
                              hipStream_t stream) {
  const float* X           = (const float*)d_in[0];
  const float* W_embed     = (const float*)d_in[1];
  const float* mask_coarse = (const float*)d_in[2];
  const float* mask_fine   = (const float*)d_in[3];
  const float* W_deconv    = (const float*)d_in[4];
  const float* w1          = (const float*)d_in[5];
  const float* w2          = (const float*)d_in[6];
  const float* w_out       = (const float*)d_in[7];
  const float* b_out       = (const float*)d_in[8];
  float* ws  = (float*)d_ws;
  float* out = (float*)d_out;

  prep_kernel<<<dim3(128), dim3(256), 0, stream>>>(X, W_embed, mask_coarse, ws);
  scan_kernel<<<dim3(256), dim3(512), 0, stream>>>(mask_fine, W_deconv, w1, w2, w_out, ws);
  final_kernel<<<dim3(512), dim3(256), 0, stream>>>(b_out, ws, out);
}